// Round 2
// baseline (2420.536 us; speedup 1.0000x reference)
//
#include <hip/hip_runtime.h>

#define BATCH 8
#define SEQ 4096
#define DIM 256
#define NH 8
#define DH 32
#define FFN_DIM 1024
#define NL 6
#define M_TOTAL (BATCH * SEQ)   // 32768
#define NCHUNK 16
#define FFN_ROWS 8192           // FFN M-chunk

typedef __attribute__((ext_vector_type(8))) short s16x8;
typedef __attribute__((ext_vector_type(4))) short s16x4;
typedef __attribute__((ext_vector_type(4))) float f32x4;

__device__ __forceinline__ float bf2f(short s) {
    union { unsigned u; float f; } x;
    x.u = ((unsigned)(unsigned short)s) << 16;
    return x.f;
}
__device__ __forceinline__ short f2bf(float f) {
    union { float f; unsigned u; } x;
    x.f = f;
    unsigned r = x.u + 0x7fffu + ((x.u >> 16) & 1u);
    return (short)(r >> 16);
}

// ---------------- positional encoding add: bf16 + fp32 dual write ----------------
__global__ void peadd_kernel(const float* __restrict__ Q, short* __restrict__ xb,
                             float* __restrict__ xf, int total)
{
    const float c = 9.210340371976184f / 256.f;  // ln(1e4)/256
    for (int idx = blockIdx.x * 256 + threadIdx.x; idx < total; idx += gridDim.x * 256) {
        int d = idx & (DIM - 1);
        int l = (idx >> 8) & (SEQ - 1);
        float rate = __expf(-(float)(d & ~1) * c);
        float ang = (float)l * rate;
        float pe = (d & 1) ? cosf(ang) : sinf(ang);
        float v = Q[idx] + pe;
        xb[idx] = f2bf(v);
        xf[idx] = v;
    }
}

__global__ void kconv_kernel(const float* __restrict__ src, short* __restrict__ dst, int total)
{
    for (int idx = blockIdx.x * 256 + threadIdx.x; idx < total; idx += gridDim.x * 256)
        dst[idx] = f2bf(src[idx]);
}

// ---------------- weight transpose + convert: Wt[n][k] = W[k][n] (layer = blockIdx.z) ----
__global__ void wtrans_kernel(const float* __restrict__ W, short* __restrict__ Wt, int K, int N)
{
    __shared__ float tile[32][33];
    int k0 = blockIdx.x * 32, n0 = blockIdx.y * 32;
    const float* Wl = W + (long)blockIdx.z * K * N;
    short* Wtl = Wt + (long)blockIdx.z * K * N;
    int tx = threadIdx.x, ty = threadIdx.y;
#pragma unroll
    for (int r = 0; r < 4; ++r)
        tile[ty + r * 8][tx] = Wl[(long)(k0 + ty + r * 8) * N + n0 + tx];
    __syncthreads();
#pragma unroll
    for (int r = 0; r < 4; ++r)
        Wtl[(long)(n0 + ty + r * 8) * K + k0 + tx] = f2bf(tile[tx][ty + r * 8]);
}

// ---------------- bf16 MFMA GEMM: Cb = act(A @ Bt^T + bias), bf16 out -------------
// A: (M,K) bf16 row-major. Bt: (N,K) bf16 row-major. ACT: 0 none, 1 elu+1, 2 relu.
#define GLDS16(gp, sp) __builtin_amdgcn_global_load_lds( \
    (const __attribute__((address_space(1))) void*)(gp), \
    (__attribute__((address_space(3))) void*)(sp), 16, 0, 0)

template<int ACT>
__global__ __launch_bounds__(256, 2) void gemm_bt_kernel(
    const short* __restrict__ A, const short* __restrict__ Bt,
    const float* __restrict__ bias, short* __restrict__ Cb,
    int M, int N, int K)
{
    __shared__ short As[4][128][8];   // [k-group][row][8 k-elems]
    __shared__ short Bs[4][128][8];
    const int tid = threadIdx.x;
    const int lane = tid & 63;
    const int wid = tid >> 6;
    const int wr = wid >> 1, wc = wid & 1;
    const int bm = blockIdx.x * 128, bn = blockIdx.y * 128;
    const int l15 = lane & 15, l4 = lane >> 4;

    const short* aSrc0 = A + (long)(bm + lane) * K + wid * 8;
    const short* aSrc1 = A + (long)(bm + 64 + lane) * K + wid * 8;
    const short* bSrc0 = Bt + (long)(bn + lane) * K + wid * 8;
    const short* bSrc1 = Bt + (long)(bn + 64 + lane) * K + wid * 8;

    f32x4 acc[4][4] = {};

    for (int k0 = 0; k0 < K; k0 += 32) {
        GLDS16(aSrc0 + k0, &As[wid][0][0]);
        GLDS16(aSrc1 + k0, &As[wid][64][0]);
        GLDS16(bSrc0 + k0, &Bs[wid][0][0]);
        GLDS16(bSrc1 + k0, &Bs[wid][64][0]);
        __syncthreads();
        s16x8 avA[4], avB[4];
#pragma unroll
        for (int m = 0; m < 4; ++m)
            avA[m] = *(const s16x8*)&As[l4][wr * 64 + m * 16 + l15][0];
#pragma unroll
        for (int n = 0; n < 4; ++n)
            avB[n] = *(const s16x8*)&Bs[l4][wc * 64 + n * 16 + l15][0];
#pragma unroll
        for (int m = 0; m < 4; ++m)
#pragma unroll
            for (int n = 0; n < 4; ++n)
                acc[m][n] = __builtin_amdgcn_mfma_f32_16x16x32_bf16(avA[m], avB[n], acc[m][n], 0, 0, 0);
        __syncthreads();
    }

#pragma unroll
    for (int m = 0; m < 4; ++m) {
        int row0 = bm + wr * 64 + m * 16 + l4 * 4;
#pragma unroll
        for (int n = 0; n < 4; ++n) {
            int col = bn + wc * 64 + n * 16 + l15;
            float bv = bias[col];
#pragma unroll
            for (int j = 0; j < 4; ++j) {
                float v = acc[m][n][j] + bv;
                if (ACT == 1) v = (v > 0.f) ? v + 1.f : __expf(v);
                else if (ACT == 2) v = fmaxf(v, 0.f);
                Cb[(long)(row0 + j) * N + col] = f2bf(v);
            }
        }
    }
}

// ---------------- KV partial reduce over 256-row chunks ----------------
__global__ __launch_bounds__(256) void kvpart_kernel(
    const short* __restrict__ Kf, const short* __restrict__ V, float* __restrict__ part)
{
    __shared__ float kfs[16][32];
    __shared__ float vsh[16][32];
    int c = blockIdx.x, bh = blockIdx.y;
    int b = bh >> 3, h = bh & 7;
    int tid = threadIdx.x;
    int d = tid >> 3, m0 = (tid & 7) * 4;
    int r = tid >> 4, cp = (tid & 15) * 2;
    float acc0 = 0, acc1 = 0, acc2 = 0, acc3 = 0, ks = 0;
    long rowBase = ((long)b * SEQ + c * 256) * DIM + h * DH;
    for (int s0 = 0; s0 < 256; s0 += 16) {
        long rb = rowBase + (long)(s0 + r) * DIM + cp;
        kfs[r][cp]     = bf2f(Kf[rb]);
        kfs[r][cp + 1] = bf2f(Kf[rb + 1]);
        vsh[r][cp]     = bf2f(V[rb]);
        vsh[r][cp + 1] = bf2f(V[rb + 1]);
        __syncthreads();
#pragma unroll
        for (int s = 0; s < 16; ++s) {
            float kd = kfs[s][d];
            acc0 += kd * vsh[s][m0];
            acc1 += kd * vsh[s][m0 + 1];
            acc2 += kd * vsh[s][m0 + 2];
            acc3 += kd * vsh[s][m0 + 3];
        }
        if (tid < 32) {
#pragma unroll
            for (int s = 0; s < 16; ++s) ks += kfs[s][tid];
        }
        __syncthreads();
    }
    float* pb = part + ((long)bh * NCHUNK + c) * 1056;
    pb[tid * 4 + 0] = acc0; pb[tid * 4 + 1] = acc1;
    pb[tid * 4 + 2] = acc2; pb[tid * 4 + 3] = acc3;
    if (tid < 32) pb[1024 + tid] = ks;
}

__global__ __launch_bounds__(256) void kvred_kernel(
    const float* __restrict__ part, float* __restrict__ kv, float* __restrict__ ksum)
{
    int bh = blockIdx.x, tid = threadIdx.x;
    const float* pb = part + (long)bh * NCHUNK * 1056;
    float s0 = 0, s1 = 0, s2 = 0, s3 = 0;
    for (int cc = 0; cc < NCHUNK; ++cc) {
        const float* p = pb + cc * 1056 + tid * 4;
        s0 += p[0]; s1 += p[1]; s2 += p[2]; s3 += p[3];
    }
    float* kb = kv + (long)bh * 1024 + tid * 4;
    kb[0] = s0; kb[1] = s1; kb[2] = s2; kb[3] = s3;
    if (tid < 32) {
        float ss = 0;
        for (int cc = 0; cc < NCHUNK; ++cc) ss += pb[cc * 1056 + 1024 + tid];
        ksum[bh * 32 + tid] = ss;
    }
}

// ---------------- attention output: out = (Qf @ KV) * Z per (b,h) -----------------
__global__ __launch_bounds__(256) void attn_kernel(
    const short* __restrict__ Qf, const float* __restrict__ kv,
    const float* __restrict__ ksum, short* __restrict__ outp)
{
    __shared__ short kvbT[32][32];   // kvbT[m][d] = KV[d][m] bf16
    __shared__ float ksumf[32];
    __shared__ float zrow[128];
    int bh = blockIdx.y, b = bh >> 3, h = bh & 7;
    int l0 = blockIdx.x * 128;
    int tid = threadIdx.x;
    for (int j = tid; j < 1024; j += 256) {
        int dd = j >> 5, mm = j & 31;
        kvbT[mm][dd] = f2bf(kv[(long)bh * 1024 + j]);
    }
    if (tid < 32) ksumf[tid] = ksum[bh * 32 + tid];
    __syncthreads();
    if (tid < 128) {
        const s16x4* qp = (const s16x4*)(Qf + ((long)(b * SEQ + l0 + tid) * DIM + h * DH));
        float den = 1e-6f;
#pragma unroll
        for (int jj = 0; jj < 8; ++jj) {
            s16x4 q4 = qp[jj];
#pragma unroll
            for (int e = 0; e < 4; ++e) den += bf2f(q4[e]) * ksumf[jj * 4 + e];
        }
        zrow[tid] = 1.f / den;
    }
    __syncthreads();
    int lane = tid & 63, wid = tid >> 6;
    int l15 = lane & 15, l4 = lane >> 4;
    s16x8 bfr[2];
#pragma unroll
    for (int n = 0; n < 2; ++n)
        bfr[n] = *(const s16x8*)&kvbT[n * 16 + l15][l4 * 8];
    f32x4 acc[2][2] = {};
#pragma unroll
    for (int m = 0; m < 2; ++m) {
        int rr = wid * 32 + m * 16 + l15;
        s16x8 a = *(const s16x8*)(Qf + ((long)(b * SEQ + l0 + rr) * DIM + h * DH + l4 * 8));
#pragma unroll
        for (int n = 0; n < 2; ++n)
            acc[m][n] = __builtin_amdgcn_mfma_f32_16x16x32_bf16(a, bfr[n], acc[m][n], 0, 0, 0);
    }
#pragma unroll
    for (int m = 0; m < 2; ++m)
#pragma unroll
        for (int n = 0; n < 2; ++n)
#pragma unroll
            for (int j = 0; j < 4; ++j) {
                int rr = wid * 32 + m * 16 + l4 * 4 + j;
                int cc = n * 16 + l15;
                float v = acc[m][n][j] * zrow[rr];
                outp[(long)(b * SEQ + l0 + rr) * DIM + h * DH + cc] = f2bf(v);
            }
}

// ---------------- fused residual + LayerNorm: y = LN(bf16(y0) + fp32 resid) -------
__global__ __launch_bounds__(256) void lnres_kernel(
    const short* __restrict__ y0, const float* __restrict__ resid,
    const float* __restrict__ g, const float* __restrict__ bb,
    short* __restrict__ ob, float* __restrict__ of)
{
    int wid = threadIdx.x >> 6, lane = threadIdx.x & 63;
    long row = (long)blockIdx.x * 4 + wid;
    int col = lane * 4;
    s16x4 yb = *(const s16x4*)(y0 + row * DIM + col);
    f32x4 r = *(const f32x4*)(resid + row * DIM + col);
    f32x4 v;
#pragma unroll
    for (int j = 0; j < 4; ++j) v[j] = bf2f(yb[j]) + r[j];
    float s = v[0] + v[1] + v[2] + v[3];
    float q = v[0] * v[0] + v[1] * v[1] + v[2] * v[2] + v[3] * v[3];
#pragma unroll
    for (int off = 1; off < 64; off <<= 1) {
        s += __shfl_xor(s, off);
        q += __shfl_xor(q, off);
    }
    float mu = s * (1.f / 256.f);
    float var = q * (1.f / 256.f) - mu * mu;
    float rs = rsqrtf(var + 1e-3f);
    s16x4 o;
    f32x4 vf;
#pragma unroll
    for (int j = 0; j < 4; ++j) {
        float t = (v[j] - mu) * rs * g[col + j] + bb[col + j];
        o[j] = f2bf(t);
        vf[j] = t;
    }
    *(s16x4*)(ob + row * DIM + col) = o;
    *(f32x4*)(of + row * DIM + col) = vf;
}

// =======================================================================================
extern "C" void kernel_launch(void* const* d_in, const int* in_sizes, int n_in,
                              void* d_out, int out_size, void* d_ws, size_t ws_size,
                              hipStream_t stream)
{
    const float* Qin = (const float*)d_in[0];
    const float* Kin = (const float*)d_in[1];
    const float* Wq1 = (const float*)d_in[2];
    const float* Wk1 = (const float*)d_in[3];
    const float* Wv1 = (const float*)d_in[4];
    const float* Wo1 = (const float*)d_in[5];
    const float* bq1 = (const float*)d_in[6];
    const float* bk1 = (const float*)d_in[7];
    const float* bv1 = (const float*)d_in[8];
    const float* bo1 = (const float*)d_in[9];
    const float* Wq2 = (const float*)d_in[10];
    const float* Wk2 = (const float*)d_in[11];
    const float* Wv2 = (const float*)d_in[12];
    const float* Wo2 = (const float*)d_in[13];
    const float* bq2 = (const float*)d_in[14];
    const float* bk2 = (const float*)d_in[15];
    const float* bv2 = (const float*)d_in[16];
    const float* bo2 = (const float*)d_in[17];
    const float* Wf1 = (const float*)d_in[18];
    const float* bf1 = (const float*)d_in[19];
    const float* Wf2 = (const float*)d_in[20];
    const float* bf2 = (const float*)d_in[21];
    const float* ln1g = (const float*)d_in[22];
    const float* ln1b = (const float*)d_in[23];
    const float* ln2g = (const float*)d_in[24];
    const float* ln2b = (const float*)d_in[25];
    const float* ln3g = (const float*)d_in[26];
    const float* ln3b = (const float*)d_in[27];
    (void)in_sizes; (void)n_in; (void)out_size;

    // ---- workspace budget: ~112.4 MiB. Guard: if ws too small, do nothing (absmax
    // will show ~4.8 on all-zero out => diagnostic that ws_size < NEED, no crash).
    const size_t NEED = 117841920ULL;
    if (ws_size < NEED) return;

    char* ws = (char*)d_ws;
    size_t off = 0;
    auto alloc = [&](size_t bytes) -> void* {
        void* p = ws + off;
        off = (off + bytes + 255) & ~(size_t)255;
        return p;
    };
    const size_t ACT_E = (size_t)M_TOTAL * DIM;  // 8388608 elems

    short* wq1t = (short*)alloc((size_t)NL * 65536 * 2);
    short* wk1t = (short*)alloc((size_t)NL * 65536 * 2);
    short* wv1t = (short*)alloc((size_t)NL * 65536 * 2);
    short* wo1t = (short*)alloc((size_t)NL * 65536 * 2);
    short* wq2t = (short*)alloc((size_t)NL * 65536 * 2);
    short* wk2t = (short*)alloc((size_t)NL * 65536 * 2);
    short* wv2t = (short*)alloc((size_t)NL * 65536 * 2);
    short* wo2t = (short*)alloc((size_t)NL * 65536 * 2);
    short* wf1t = (short*)alloc((size_t)NL * 262144 * 2);
    short* wf2t = (short*)alloc((size_t)NL * 262144 * 2);
    short* kbf = (short*)alloc(ACT_E * 2);   // K as bf16 (all layers)
    short* A0 = (short*)alloc(ACT_E * 2);    // current x (bf16)
    short* A2 = (short*)alloc(ACT_E * 2);    // Kf / Qf / y0 / f
    short* A3 = (short*)alloc(ACT_E * 2);    // Vf / attnout / FFN hidden chunk
    float* Fx = (float*)alloc(ACT_E * 4);    // current x (fp32 residual path)
    float* part = (float*)alloc((size_t)64 * NCHUNK * 1056 * 4);
    float* kvb = (float*)alloc((size_t)64 * 1024 * 4);
    float* ksb = (float*)alloc((size_t)64 * 32 * 4);

    peadd_kernel<<<2048, 256, 0, stream>>>(Qin, A0, Fx, (int)ACT_E);
    kconv_kernel<<<2048, 256, 0, stream>>>(Kin, kbf, (int)ACT_E);
    wtrans_kernel<<<dim3(8, 8, NL), dim3(32, 8), 0, stream>>>(Wq1, wq1t, 256, 256);
    wtrans_kernel<<<dim3(8, 8, NL), dim3(32, 8), 0, stream>>>(Wk1, wk1t, 256, 256);
    wtrans_kernel<<<dim3(8, 8, NL), dim3(32, 8), 0, stream>>>(Wv1, wv1t, 256, 256);
    wtrans_kernel<<<dim3(8, 8, NL), dim3(32, 8), 0, stream>>>(Wo1, wo1t, 256, 256);
    wtrans_kernel<<<dim3(8, 8, NL), dim3(32, 8), 0, stream>>>(Wq2, wq2t, 256, 256);
    wtrans_kernel<<<dim3(8, 8, NL), dim3(32, 8), 0, stream>>>(Wk2, wk2t, 256, 256);
    wtrans_kernel<<<dim3(8, 8, NL), dim3(32, 8), 0, stream>>>(Wv2, wv2t, 256, 256);
    wtrans_kernel<<<dim3(8, 8, NL), dim3(32, 8), 0, stream>>>(Wo2, wo2t, 256, 256);
    wtrans_kernel<<<dim3(8, 32, NL), dim3(32, 8), 0, stream>>>(Wf1, wf1t, 256, 1024);
    wtrans_kernel<<<dim3(32, 8, NL), dim3(32, 8), 0, stream>>>(Wf2, wf2t, 1024, 256);

    dim3 g256(256, 2), blk(256);

    for (int i = 0; i < NL; ++i) {
        const short* wq1i = wq1t + (size_t)i * 65536;
        const short* wk1i = wk1t + (size_t)i * 65536;
        const short* wv1i = wv1t + (size_t)i * 65536;
        const short* wo1i = wo1t + (size_t)i * 65536;
        const short* wq2i = wq2t + (size_t)i * 65536;
        const short* wk2i = wk2t + (size_t)i * 65536;
        const short* wv2i = wv2t + (size_t)i * 65536;
        const short* wo2i = wo2t + (size_t)i * 65536;
        const short* wf1i = wf1t + (size_t)i * 262144;
        const short* wf2i = wf2t + (size_t)i * 262144;

        // ---- self linear-attention (x1 -> x2)
        gemm_bt_kernel<1><<<g256, blk, 0, stream>>>(A0, wk1i, bk1 + i * 256, A2, M_TOTAL, 256, 256);
        gemm_bt_kernel<0><<<g256, blk, 0, stream>>>(A0, wv1i, bv1 + i * 256, A3, M_TOTAL, 256, 256);
        kvpart_kernel<<<dim3(NCHUNK, 64), blk, 0, stream>>>(A2, A3, part);
        kvred_kernel<<<64, blk, 0, stream>>>(part, kvb, ksb);
        gemm_bt_kernel<1><<<g256, blk, 0, stream>>>(A0, wq1i, bq1 + i * 256, A2, M_TOTAL, 256, 256);
        attn_kernel<<<dim3(SEQ / 128, 64), blk, 0, stream>>>(A2, kvb, ksb, A3);
        gemm_bt_kernel<0><<<g256, blk, 0, stream>>>(A3, wo1i, bo1 + i * 256, A2, M_TOTAL, 256, 256);
        lnres_kernel<<<M_TOTAL / 4, blk, 0, stream>>>(A2, Fx, ln1g + i * 256, ln1b + i * 256, A0, Fx);

        // ---- cross linear-attention (x2, K -> x3)
        gemm_bt_kernel<1><<<g256, blk, 0, stream>>>(kbf, wk2i, bk2 + i * 256, A2, M_TOTAL, 256, 256);
        gemm_bt_kernel<0><<<g256, blk, 0, stream>>>(kbf, wv2i, bv2 + i * 256, A3, M_TOTAL, 256, 256);
        kvpart_kernel<<<dim3(NCHUNK, 64), blk, 0, stream>>>(A2, A3, part);
        kvred_kernel<<<64, blk, 0, stream>>>(part, kvb, ksb);
        gemm_bt_kernel<1><<<g256, blk, 0, stream>>>(A0, wq2i, bq2 + i * 256, A2, M_TOTAL, 256, 256);
        attn_kernel<<<dim3(SEQ / 128, 64), blk, 0, stream>>>(A2, kvb, ksb, A3);
        gemm_bt_kernel<0><<<g256, blk, 0, stream>>>(A3, wo2i, bo2 + i * 256, A2, M_TOTAL, 256, 256);
        lnres_kernel<<<M_TOTAL / 4, blk, 0, stream>>>(A2, Fx, ln2g + i * 256, ln2b + i * 256, A0, Fx);

        // ---- FFN (x3 -> x1'), 4 row-chunks: hidden in A3, f into A2
        for (int c = 0; c < 4; ++c) {
            const short* xA = A0 + (size_t)c * FFN_ROWS * DIM;
            short* fA = A2 + (size_t)c * FFN_ROWS * DIM;
            gemm_bt_kernel<2><<<dim3(FFN_ROWS / 128, FFN_DIM / 128), blk, 0, stream>>>(
                xA, wf1i, bf1 + i * 1024, A3, FFN_ROWS, FFN_DIM, 256);
            gemm_bt_kernel<2><<<dim3(FFN_ROWS / 128, 2), blk, 0, stream>>>(
                A3, wf2i, bf2 + i * 256, fA, FFN_ROWS, 256, 1024);
        }
        lnres_kernel<<<M_TOTAL / 4, blk, 0, stream>>>(A2, Fx, ln3g + i * 256, ln3b + i * 256, A0,
                                                      (i == NL - 1) ? (float*)d_out : Fx);
    }
}

// Round 4
// 2079.942 us; speedup vs baseline: 1.1638x; 1.1638x over previous
//
#include <hip/hip_runtime.h>

#define BATCH 8
#define SEQ 4096
#define DIM 256
#define NH 8
#define DH 32
#define FFN_DIM 1024
#define NL 6
#define M_TOTAL (BATCH * SEQ)   // 32768
#define NCHUNK 8
#define FFN_ROWS 16384          // FFN M-chunk (hidden = 16384x1024 bf16 = 33.55 MB = BIG)

typedef __attribute__((ext_vector_type(8))) short s16x8;
typedef __attribute__((ext_vector_type(4))) short s16x4;
typedef __attribute__((ext_vector_type(4))) float f32x4;

__device__ __forceinline__ float bf2f(short s) {
    union { unsigned u; float f; } x;
    x.u = ((unsigned)(unsigned short)s) << 16;
    return x.f;
}
__device__ __forceinline__ short f2bf(float f) {
    union { float f; unsigned u; } x;
    x.f = f;
    unsigned r = x.u + 0x7fffu + ((x.u >> 16) & 1u);
    return (short)(r >> 16);
}

#define GLDS16(gp, sp) __builtin_amdgcn_global_load_lds( \
    (const __attribute__((address_space(1))) void*)(gp), \
    (__attribute__((address_space(3))) void*)(sp), 16, 0, 0)

// ---------------- positional encoding add: bf16 + fp32 dual write ----------------
__global__ void peadd_kernel(const float* __restrict__ Q, short* __restrict__ xb,
                             float* __restrict__ xf, int total)
{
    const float c = 9.210340371976184f / 256.f;  // ln(1e4)/256
    for (int idx = blockIdx.x * 256 + threadIdx.x; idx < total; idx += gridDim.x * 256) {
        int d = idx & (DIM - 1);
        int l = (idx >> 8) & (SEQ - 1);
        float rate = __expf(-(float)(d & ~1) * c);
        float ang = (float)l * rate;
        float pe = (d & 1) ? cosf(ang) : sinf(ang);
        float v = Q[idx] + pe;
        xb[idx] = f2bf(v);
        xf[idx] = v;
    }
}

__global__ void kconv_kernel(const float* __restrict__ src, short* __restrict__ dst, int total)
{
    for (int idx = blockIdx.x * 256 + threadIdx.x; idx < total; idx += gridDim.x * 256)
        dst[idx] = f2bf(src[idx]);
}

// ---- weight transpose+convert: Wt[lstride*z + (rowoff+n)*K + k] = W[z][k][n] ----
__global__ void wtrans_kernel(const float* __restrict__ W, short* __restrict__ Wt,
                              int K, int N, int lstride, int rowoff)
{
    __shared__ float tile[32][33];
    int k0 = blockIdx.x * 32, n0 = blockIdx.y * 32;
    const float* Wl = W + (long)blockIdx.z * K * N;
    short* Wtl = Wt + (long)blockIdx.z * lstride;
    int tx = threadIdx.x, ty = threadIdx.y;
#pragma unroll
    for (int r = 0; r < 4; ++r)
        tile[ty + r * 8][tx] = Wl[(long)(k0 + ty + r * 8) * N + n0 + tx];
    __syncthreads();
#pragma unroll
    for (int r = 0; r < 4; ++r)
        Wtl[(long)(rowoff + n0 + ty + r * 8) * K + k0 + tx] = f2bf(tile[tx][ty + r * 8]);
}

// ---- bias pack: bkv[z][0:256]=bk[z], [256:512]=bv[z] for both attn stacks ----
__global__ void bpack_kernel(const float* __restrict__ bk1, const float* __restrict__ bv1,
                             const float* __restrict__ bk2, const float* __restrict__ bv2,
                             float* __restrict__ o1, float* __restrict__ o2)
{
    int z = blockIdx.x, t = threadIdx.x;
    o1[z * 512 + t] = (t < 256) ? bk1[z * 256 + t] : bv1[z * 256 + t - 256];
    o2[z * 512 + t] = (t < 256) ? bk2[z * 256 + t] : bv2[z * 256 + t - 256];
}

// ---------------- bf16 MFMA GEMM: Cb = act(A @ Bt^T + bias), bf16 out -------------
// A: (M,K) bf16, row stride lda. Bt: (N,K) bf16. ACT: 0 none, 1 elu+1 for col<eluCut, 2 relu.
template<int ACT>
__global__ __launch_bounds__(256, 2) void gemm_bt_kernel(
    const short* __restrict__ A, const short* __restrict__ Bt,
    const float* __restrict__ bias, short* __restrict__ Cb,
    int N, int K, int lda, int ldc, int eluCut)
{
    __shared__ short As[4][128][8];   // [k-group][row][8 k-elems]
    __shared__ short Bs[4][128][8];
    const int tid = threadIdx.x;
    const int lane = tid & 63;
    const int wid = tid >> 6;
    const int wr = wid >> 1, wc = wid & 1;
    const int bm = blockIdx.x * 128, bn = blockIdx.y * 128;
    const int l15 = lane & 15, l4 = lane >> 4;

    const short* aSrc0 = A + (long)(bm + lane) * lda + wid * 8;
    const short* aSrc1 = A + (long)(bm + 64 + lane) * lda + wid * 8;
    const short* bSrc0 = Bt + (long)(bn + lane) * K + wid * 8;
    const short* bSrc1 = Bt + (long)(bn + 64 + lane) * K + wid * 8;

    f32x4 acc[4][4] = {};

    for (int k0 = 0; k0 < K; k0 += 32) {
        GLDS16(aSrc0 + k0, &As[wid][0][0]);
        GLDS16(aSrc1 + k0, &As[wid][64][0]);
        GLDS16(bSrc0 + k0, &Bs[wid][0][0]);
        GLDS16(bSrc1 + k0, &Bs[wid][64][0]);
        __syncthreads();
        s16x8 avA[4], avB[4];
#pragma unroll
        for (int m = 0; m < 4; ++m)
            avA[m] = *(const s16x8*)&As[l4][wr * 64 + m * 16 + l15][0];
#pragma unroll
        for (int n = 0; n < 4; ++n)
            avB[n] = *(const s16x8*)&Bs[l4][wc * 64 + n * 16 + l15][0];
#pragma unroll
        for (int m = 0; m < 4; ++m)
#pragma unroll
            for (int n = 0; n < 4; ++n)
                acc[m][n] = __builtin_amdgcn_mfma_f32_16x16x32_bf16(avA[m], avB[n], acc[m][n], 0, 0, 0);
        __syncthreads();
    }

#pragma unroll
    for (int m = 0; m < 4; ++m) {
        int row0 = bm + wr * 64 + m * 16 + l4 * 4;
#pragma unroll
        for (int n = 0; n < 4; ++n) {
            int col = bn + wc * 64 + n * 16 + l15;
            float bv = bias[col];
#pragma unroll
            for (int j = 0; j < 4; ++j) {
                float v = acc[m][n][j] + bv;
                if (ACT == 1) { if (col < eluCut) v = (v > 0.f) ? v + 1.f : __expf(v); }
                else if (ACT == 2) v = fmaxf(v, 0.f);
                Cb[(long)(row0 + j) * ldc + col] = f2bf(v);
            }
        }
    }
}

// ---- fused GEMM + bias + act + residual + LayerNorm (BM=64, BN=256 full row) ----
// out row = LN(act(A@Bt^T + bias) + Fin[row]); writes bf16 xb and f32 Fout.
template<int ACT>
__global__ __launch_bounds__(256, 2) void gemmln_kernel(
    const short* __restrict__ A, const short* __restrict__ Bt,
    const float* __restrict__ bias,
    const float* __restrict__ gam, const float* __restrict__ bet,
    const float* __restrict__ Fin, float* __restrict__ Fout,
    short* __restrict__ xb, int K, int lda)
{
    __shared__ short As[4][64][8];
    __shared__ short Bs[4][256][8];
    __shared__ float partS[4][64];
    __shared__ float partQ[4][64];
    __shared__ float muA[64];
    __shared__ float rsA[64];
    const int tid = threadIdx.x;
    const int lane = tid & 63;
    const int w = tid >> 6;          // wave = column block (w*64)
    const int bm = blockIdx.x * 64;
    const int l15 = lane & 15, l4 = lane >> 4;

    const short* aSrc = A + (long)(bm + lane) * lda + w * 8;

    f32x4 acc[4][4] = {};

    for (int k0 = 0; k0 < K; k0 += 32) {
        // A: wave w stages k-group w for all 64 rows (wave-uniform LDS base)
        GLDS16(aSrc + k0, &As[w][0][0]);
        // B: wave w stages ITS OWN column slice [w*64, w*64+64) for each k-group i.
        // LDS base &Bs[i][w*64][0] is wave-uniform; global address is per-lane.
#pragma unroll
        for (int i = 0; i < 4; ++i)
            GLDS16(Bt + (long)(w * 64 + lane) * K + k0 + i * 8, &Bs[i][w * 64][0]);
        __syncthreads();
        s16x8 avA[4], avB[4];
#pragma unroll
        for (int m = 0; m < 4; ++m)
            avA[m] = *(const s16x8*)&As[l4][m * 16 + l15][0];
#pragma unroll
        for (int n = 0; n < 4; ++n)
            avB[n] = *(const s16x8*)&Bs[l4][w * 64 + n * 16 + l15][0];
#pragma unroll
        for (int m = 0; m < 4; ++m)
#pragma unroll
            for (int n = 0; n < 4; ++n)
                acc[m][n] = __builtin_amdgcn_mfma_f32_16x16x32_bf16(avA[m], avB[n], acc[m][n], 0, 0, 0);
        __syncthreads();
    }

    // epilogue: bias + act + residual, then row LN across the 4 waves
#pragma unroll
    for (int m = 0; m < 4; ++m) {
#pragma unroll
        for (int n = 0; n < 4; ++n) {
            int col = w * 64 + n * 16 + l15;
            float bv = bias[col];
#pragma unroll
            for (int j = 0; j < 4; ++j) {
                int r = m * 16 + l4 * 4 + j;
                float v = acc[m][n][j] + bv;
                if (ACT == 2) v = fmaxf(v, 0.f);
                v += Fin[(long)(bm + r) * DIM + col];
                acc[m][n][j] = v;
            }
        }
    }
#pragma unroll
    for (int m = 0; m < 4; ++m)
#pragma unroll
        for (int j = 0; j < 4; ++j) {
            float s = acc[m][0][j] + acc[m][1][j] + acc[m][2][j] + acc[m][3][j];
            float q = acc[m][0][j] * acc[m][0][j] + acc[m][1][j] * acc[m][1][j]
                    + acc[m][2][j] * acc[m][2][j] + acc[m][3][j] * acc[m][3][j];
#pragma unroll
            for (int off = 1; off < 16; off <<= 1) {
                s += __shfl_xor(s, off);
                q += __shfl_xor(q, off);
            }
            if (l15 == 0) {
                partS[w][m * 16 + l4 * 4 + j] = s;
                partQ[w][m * 16 + l4 * 4 + j] = q;
            }
        }
    __syncthreads();
    if (tid < 64) {
        float S = partS[0][tid] + partS[1][tid] + partS[2][tid] + partS[3][tid];
        float Qq = partQ[0][tid] + partQ[1][tid] + partQ[2][tid] + partQ[3][tid];
        float mu = S * (1.f / 256.f);
        float var = Qq * (1.f / 256.f) - mu * mu;
        muA[tid] = mu;
        rsA[tid] = rsqrtf(var + 1e-3f);
    }
    __syncthreads();
#pragma unroll
    for (int m = 0; m < 4; ++m)
#pragma unroll
        for (int j = 0; j < 4; ++j) {
            int r = m * 16 + l4 * 4 + j;
            float mu = muA[r], rs = rsA[r];
#pragma unroll
            for (int n = 0; n < 4; ++n) {
                int col = w * 64 + n * 16 + l15;
                float t = (acc[m][n][j] - mu) * rs * gam[col] + bet[col];
                long o = (long)(bm + r) * DIM + col;
                xb[o] = f2bf(t);
                Fout[o] = t;
            }
        }
}

// ---------------- KV partial reduce: 512-row chunks, interleaved (M,512) KV buffer ----
__global__ __launch_bounds__(256) void kvpart_kernel(
    const short* __restrict__ KV, float* __restrict__ part)
{
    __shared__ float kfs[32][32];
    __shared__ float vsh[32][32];
    int c = blockIdx.x, bh = blockIdx.y;
    int b = bh >> 3, h = bh & 7;
    int tid = threadIdx.x;
    int d = tid >> 3, m0 = (tid & 7) * 4;
    float acc0 = 0, acc1 = 0, acc2 = 0, acc3 = 0, ks = 0;
    long rowBase = ((long)b * SEQ + c * 512) * 512 + h * DH;
    int lrow = (tid & 127) >> 2, cg = tid & 3;
    for (int s0 = 0; s0 < 512; s0 += 32) {
        long rb = rowBase + (long)(s0 + lrow) * 512 + cg * 8 + ((tid < 128) ? 0 : 256);
        s16x8 v8 = *(const s16x8*)(KV + rb);
        float* dst = (tid < 128) ? &kfs[lrow][cg * 8] : &vsh[lrow][cg * 8];
#pragma unroll
        for (int e = 0; e < 8; ++e) dst[e] = bf2f(v8[e]);
        __syncthreads();
#pragma unroll
        for (int s = 0; s < 32; ++s) {
            float kd = kfs[s][d];
            acc0 += kd * vsh[s][m0];
            acc1 += kd * vsh[s][m0 + 1];
            acc2 += kd * vsh[s][m0 + 2];
            acc3 += kd * vsh[s][m0 + 3];
        }
        if (tid < 32) {
#pragma unroll
            for (int s = 0; s < 32; ++s) ks += kfs[s][tid];
        }
        __syncthreads();
    }
    float* pb = part + ((long)bh * NCHUNK + c) * 1056;
    pb[tid * 4 + 0] = acc0; pb[tid * 4 + 1] = acc1;
    pb[tid * 4 + 2] = acc2; pb[tid * 4 + 3] = acc3;
    if (tid < 32) pb[1024 + tid] = ks;
}

__global__ __launch_bounds__(256) void kvred_kernel(
    const float* __restrict__ part, float* __restrict__ kv, float* __restrict__ ksum)
{
    int bh = blockIdx.x, tid = threadIdx.x;
    const float* pb = part + (long)bh * NCHUNK * 1056;
    float s0 = 0, s1 = 0, s2 = 0, s3 = 0;
    for (int cc = 0; cc < NCHUNK; ++cc) {
        const float* p = pb + cc * 1056 + tid * 4;
        s0 += p[0]; s1 += p[1]; s2 += p[2]; s3 += p[3];
    }
    float* kb = kv + (long)bh * 1024 + tid * 4;
    kb[0] = s0; kb[1] = s1; kb[2] = s2; kb[3] = s3;
    if (tid < 32) {
        float ss = 0;
        for (int cc = 0; cc < NCHUNK; ++cc) ss += pb[cc * 1056 + 1024 + tid];
        ksum[bh * 32 + tid] = ss;
    }
}

// ---------------- attention output: out = (Qf @ KV) * Z per (b,h); ld=512 -----------
__global__ __launch_bounds__(256) void attn_kernel(
    const short* __restrict__ Qf, const float* __restrict__ kv,
    const float* __restrict__ ksum, short* __restrict__ outp)
{
    __shared__ short kvbT[32][32];   // kvbT[m][d] = KV[d][m] bf16
    __shared__ float ksumf[32];
    __shared__ float zrow[128];
    const int LD = 512;
    int bh = blockIdx.y, b = bh >> 3, h = bh & 7;
    int l0 = blockIdx.x * 128;
    int tid = threadIdx.x;
    for (int j = tid; j < 1024; j += 256) {
        int dd = j >> 5, mm = j & 31;
        kvbT[mm][dd] = f2bf(kv[(long)bh * 1024 + j]);
    }
    if (tid < 32) ksumf[tid] = ksum[bh * 32 + tid];
    __syncthreads();
    if (tid < 128) {
        const s16x4* qp = (const s16x4*)(Qf + ((long)(b * SEQ + l0 + tid) * LD + h * DH));
        float den = 1e-6f;
#pragma unroll
        for (int jj = 0; jj < 8; ++jj) {
            s16x4 q4 = qp[jj];
#pragma unroll
            for (int e = 0; e < 4; ++e) den += bf2f(q4[e]) * ksumf[jj * 4 + e];
        }
        zrow[tid] = 1.f / den;
    }
    __syncthreads();
    int lane = tid & 63, wid = tid >> 6;
    int l15 = lane & 15, l4 = lane >> 4;
    s16x8 bfr[2];
#pragma unroll
    for (int n = 0; n < 2; ++n)
        bfr[n] = *(const s16x8*)&kvbT[n * 16 + l15][l4 * 8];
    f32x4 acc[2][2] = {};
#pragma unroll
    for (int m = 0; m < 2; ++m) {
        int rr = wid * 32 + m * 16 + l15;
        s16x8 a = *(const s16x8*)(Qf + ((long)(b * SEQ + l0 + rr) * LD + h * DH + l4 * 8));
#pragma unroll
        for (int n = 0; n < 2; ++n)
            acc[m][n] = __builtin_amdgcn_mfma_f32_16x16x32_bf16(a, bfr[n], acc[m][n], 0, 0, 0);
    }
#pragma unroll
    for (int m = 0; m < 2; ++m)
#pragma unroll
        for (int n = 0; n < 2; ++n)
#pragma unroll
            for (int j = 0; j < 4; ++j) {
                int rr = wid * 32 + m * 16 + l4 * 4 + j;
                int cc = n * 16 + l15;
                float v = acc[m][n][j] * zrow[rr];
                outp[(long)(b * SEQ + l0 + rr) * LD + h * DH + cc] = f2bf(v);
            }
}

// =======================================================================================
extern "C" void kernel_launch(void* const* d_in, const int* in_sizes, int n_in,
                              void* d_out, int out_size, void* d_ws, size_t ws_size,
                              hipStream_t stream)
{
    const float* Qin = (const float*)d_in[0];
    const float* Kin = (const float*)d_in[1];
    const float* Wq1 = (const float*)d_in[2];
    const float* Wk1 = (const float*)d_in[3];
    const float* Wv1 = (const float*)d_in[4];
    const float* Wo1 = (const float*)d_in[5];
    const float* bq1 = (const float*)d_in[6];
    const float* bk1 = (const float*)d_in[7];
    const float* bv1 = (const float*)d_in[8];
    const float* bo1 = (const float*)d_in[9];
    const float* Wq2 = (const float*)d_in[10];
    const float* Wk2 = (const float*)d_in[11];
    const float* Wv2 = (const float*)d_in[12];
    const float* Wo2 = (const float*)d_in[13];
    const float* bq2 = (const float*)d_in[14];
    const float* bk2 = (const float*)d_in[15];
    const float* bv2 = (const float*)d_in[16];
    const float* bo2 = (const float*)d_in[17];
    const float* Wf1 = (const float*)d_in[18];
    const float* bf1 = (const float*)d_in[19];
    const float* Wf2 = (const float*)d_in[20];
    const float* bf2 = (const float*)d_in[21];
    const float* ln1g = (const float*)d_in[22];
    const float* ln1b = (const float*)d_in[23];
    const float* ln2g = (const float*)d_in[24];
    const float* ln2b = (const float*)d_in[25];
    const float* ln3g = (const float*)d_in[26];
    const float* ln3b = (const float*)d_in[27];
    (void)in_sizes; (void)n_in; (void)out_size;

    const size_t NEED = 117841920ULL;   // proven budget from round 2; actual use ~115.8 MB
    if (ws_size < NEED) return;

    char* ws = (char*)d_ws;
    size_t off = 0;
    auto alloc = [&](size_t bytes) -> void* {
        void* p = ws + off;
        off = (off + bytes + 255) & ~(size_t)255;
        return p;
    };
    const size_t ACT_E = (size_t)M_TOTAL * DIM;  // 8388608 elems

    short* wkv1t = (short*)alloc((size_t)NL * 512 * 256 * 2);   // [Wk;Wv] stack, layer stride 512*256
    short* wkv2t = (short*)alloc((size_t)NL * 512 * 256 * 2);
    short* wq1t  = (short*)alloc((size_t)NL * 65536 * 2);
    short* wo1t  = (short*)alloc((size_t)NL * 65536 * 2);
    short* wq2t  = (short*)alloc((size_t)NL * 65536 * 2);
    short* wo2t  = (short*)alloc((size_t)NL * 65536 * 2);
    short* wf1t  = (short*)alloc((size_t)NL * 262144 * 2);
    short* wf2t  = (short*)alloc((size_t)NL * 262144 * 2);
    float* bkv1  = (float*)alloc((size_t)NL * 512 * 4);
    float* bkv2  = (float*)alloc((size_t)NL * 512 * 4);
    short* kbf = (short*)alloc(ACT_E * 2);          // K input as bf16
    short* A0  = (short*)alloc(ACT_E * 2);          // current x (bf16)
    short* BIG = (short*)alloc((size_t)M_TOTAL * 512 * 2);  // KV/Q/attnout | FFN hidden
    float* Fx  = (float*)alloc(ACT_E * 4);          // fp32 residual trunk
    float* part = (float*)alloc((size_t)64 * NCHUNK * 1056 * 4);
    float* kvb  = (float*)alloc((size_t)64 * 1024 * 4);
    float* ksb  = (float*)alloc((size_t)64 * 32 * 4);

    peadd_kernel<<<2048, 256, 0, stream>>>(Qin, A0, Fx, (int)ACT_E);
    kconv_kernel<<<2048, 256, 0, stream>>>(Kin, kbf, (int)ACT_E);
    wtrans_kernel<<<dim3(8, 8, NL), dim3(32, 8), 0, stream>>>(Wk1, wkv1t, 256, 256, 512 * 256, 0);
    wtrans_kernel<<<dim3(8, 8, NL), dim3(32, 8), 0, stream>>>(Wv1, wkv1t, 256, 256, 512 * 256, 256);
    wtrans_kernel<<<dim3(8, 8, NL), dim3(32, 8), 0, stream>>>(Wk2, wkv2t, 256, 256, 512 * 256, 0);
    wtrans_kernel<<<dim3(8, 8, NL), dim3(32, 8), 0, stream>>>(Wv2, wkv2t, 256, 256, 512 * 256, 256);
    wtrans_kernel<<<dim3(8, 8, NL), dim3(32, 8), 0, stream>>>(Wq1, wq1t, 256, 256, 65536, 0);
    wtrans_kernel<<<dim3(8, 8, NL), dim3(32, 8), 0, stream>>>(Wo1, wo1t, 256, 256, 65536, 0);
    wtrans_kernel<<<dim3(8, 8, NL), dim3(32, 8), 0, stream>>>(Wq2, wq2t, 256, 256, 65536, 0);
    wtrans_kernel<<<dim3(8, 8, NL), dim3(32, 8), 0, stream>>>(Wo2, wo2t, 256, 256, 65536, 0);
    wtrans_kernel<<<dim3(8, 32, NL), dim3(32, 8), 0, stream>>>(Wf1, wf1t, 256, 1024, 262144, 0);
    wtrans_kernel<<<dim3(32, 8, NL), dim3(32, 8), 0, stream>>>(Wf2, wf2t, 1024, 256, 262144, 0);
    bpack_kernel<<<NL, 512, 0, stream>>>(bk1, bv1, bk2, bv2, bkv1, bkv2);

    dim3 blk(256);

    for (int i = 0; i < NL; ++i) {
        const short* wkv1i = wkv1t + (size_t)i * 512 * 256;
        const short* wkv2i = wkv2t + (size_t)i * 512 * 256;
        const short* wq1i = wq1t + (size_t)i * 65536;
        const short* wo1i = wo1t + (size_t)i * 65536;
        const short* wq2i = wq2t + (size_t)i * 65536;
        const short* wo2i = wo2t + (size_t)i * 65536;
        const short* wf1i = wf1t + (size_t)i * 262144;
        const short* wf2i = wf2t + (size_t)i * 262144;

        // ---- self linear-attention (x1 -> x2)
        gemm_bt_kernel<1><<<dim3(256, 4), blk, 0, stream>>>(A0, wkv1i, bkv1 + i * 512, BIG, 512, 256, 256, 512, 256);
        kvpart_kernel<<<dim3(NCHUNK, 64), blk, 0, stream>>>(BIG, part);
        kvred_kernel<<<64, blk, 0, stream>>>(part, kvb, ksb);
        gemm_bt_kernel<1><<<dim3(256, 2), blk, 0, stream>>>(A0, wq1i, bq1 + i * 256, BIG, 256, 256, 256, 512, 256);
        attn_kernel<<<dim3(SEQ / 128, 64), blk, 0, stream>>>(BIG, kvb, ksb, BIG + 256);
        gemmln_kernel<0><<<M_TOTAL / 64, blk, 0, stream>>>(BIG + 256, wo1i, bo1 + i * 256,
            ln1g + i * 256, ln1b + i * 256, Fx, Fx, A0, 256, 512);

        // ---- cross linear-attention (x2, K -> x3)
        gemm_bt_kernel<1><<<dim3(256, 4), blk, 0, stream>>>(kbf, wkv2i, bkv2 + i * 512, BIG, 512, 256, 256, 512, 256);
        kvpart_kernel<<<dim3(NCHUNK, 64), blk, 0, stream>>>(BIG, part);
        kvred_kernel<<<64, blk, 0, stream>>>(part, kvb, ksb);
        gemm_bt_kernel<1><<<dim3(256, 2), blk, 0, stream>>>(A0, wq2i, bq2 + i * 256, BIG, 256, 256, 256, 512, 256);
        attn_kernel<<<dim3(SEQ / 128, 64), blk, 0, stream>>>(BIG, kvb, ksb, BIG + 256);
        gemmln_kernel<0><<<M_TOTAL / 64, blk, 0, stream>>>(BIG + 256, wo2i, bo2 + i * 256,
            ln2g + i * 256, ln2b + i * 256, Fx, Fx, A0, 256, 512);

        // ---- FFN (x3 -> x1'), 2 chunks of 16384 rows; hidden reuses BIG
        for (int c = 0; c < 2; ++c) {
            const size_t ro = (size_t)c * FFN_ROWS * DIM;
            gemm_bt_kernel<2><<<dim3(FFN_ROWS / 128, 8), blk, 0, stream>>>(
                A0 + ro, wf1i, bf1 + i * 1024, BIG, 1024, 256, 256, 1024, 0);
            float* foutC = ((i == NL - 1) ? (float*)d_out : Fx) + ro;
            gemmln_kernel<2><<<FFN_ROWS / 64, blk, 0, stream>>>(BIG, wf2i, bf2 + i * 256,
                ln3g + i * 256, ln3b + i * 256, Fx + ro, foutC, A0 + ro, 1024, 1024);
        }
    }
}

// Round 5
// 2046.210 us; speedup vs baseline: 1.1829x; 1.0165x over previous
//
#include <hip/hip_runtime.h>

#define BATCH 8
#define SEQ 4096
#define DIM 256
#define NH 8
#define DH 32
#define FFN_DIM 1024
#define NL 6
#define M_TOTAL (BATCH * SEQ)   // 32768
#define NCHUNK 8
#define FFN_ROWS 16384          // FFN M-chunk (hidden = 16384x1024 bf16 = 33.55 MB = BIG)

typedef __attribute__((ext_vector_type(8))) short s16x8;
typedef __attribute__((ext_vector_type(4))) short s16x4;
typedef __attribute__((ext_vector_type(4))) float f32x4;

__device__ __forceinline__ float bf2f(short s) {
    union { unsigned u; float f; } x;
    x.u = ((unsigned)(unsigned short)s) << 16;
    return x.f;
}
__device__ __forceinline__ short f2bf(float f) {
    union { float f; unsigned u; } x;
    x.f = f;
    unsigned r = x.u + 0x7fffu + ((x.u >> 16) & 1u);
    return (short)(r >> 16);
}

#define GLDS16(gp, sp) __builtin_amdgcn_global_load_lds( \
    (const __attribute__((address_space(1))) void*)(gp), \
    (__attribute__((address_space(3))) void*)(sp), 16, 0, 0)

// ---------------- positional encoding add: bf16 + fp32 dual write ----------------
__global__ void peadd_kernel(const float* __restrict__ Q, short* __restrict__ xb,
                             float* __restrict__ xf, int total)
{
    const float c = 9.210340371976184f / 256.f;  // ln(1e4)/256
    for (int idx = blockIdx.x * 256 + threadIdx.x; idx < total; idx += gridDim.x * 256) {
        int d = idx & (DIM - 1);
        int l = (idx >> 8) & (SEQ - 1);
        float rate = __expf(-(float)(d & ~1) * c);
        float ang = (float)l * rate;
        float pe = (d & 1) ? cosf(ang) : sinf(ang);
        float v = Q[idx] + pe;
        xb[idx] = f2bf(v);
        xf[idx] = v;
    }
}

__global__ void kconv_kernel(const float* __restrict__ src, short* __restrict__ dst, int total)
{
    for (int idx = blockIdx.x * 256 + threadIdx.x; idx < total; idx += gridDim.x * 256)
        dst[idx] = f2bf(src[idx]);
}

// ---- weight transpose+convert: Wt[lstride*z + (rowoff+n)*K + k] = W[z][k][n] ----
__global__ void wtrans_kernel(const float* __restrict__ W, short* __restrict__ Wt,
                              int K, int N, int lstride, int rowoff)
{
    __shared__ float tile[32][33];
    int k0 = blockIdx.x * 32, n0 = blockIdx.y * 32;
    const float* Wl = W + (long)blockIdx.z * K * N;
    short* Wtl = Wt + (long)blockIdx.z * lstride;
    int tx = threadIdx.x, ty = threadIdx.y;
#pragma unroll
    for (int r = 0; r < 4; ++r)
        tile[ty + r * 8][tx] = Wl[(long)(k0 + ty + r * 8) * N + n0 + tx];
    __syncthreads();
#pragma unroll
    for (int r = 0; r < 4; ++r)
        Wtl[(long)(rowoff + n0 + ty + r * 8) * K + k0 + tx] = f2bf(tile[tx][ty + r * 8]);
}

// ---- bias pack: bkv[z][0:256]=bk[z], [256:512]=bv[z] for both attn stacks ----
__global__ void bpack_kernel(const float* __restrict__ bk1, const float* __restrict__ bv1,
                             const float* __restrict__ bk2, const float* __restrict__ bv2,
                             float* __restrict__ o1, float* __restrict__ o2)
{
    int z = blockIdx.x, t = threadIdx.x;
    o1[z * 512 + t] = (t < 256) ? bk1[z * 256 + t] : bv1[z * 256 + t - 256];
    o2[z * 512 + t] = (t < 256) ? bk2[z * 256 + t] : bv2[z * 256 + t - 256];
}

// ---------------- bf16 MFMA GEMM: Cb = act(A @ Bt^T + bias), bf16 out -------------
// A: (M,K) bf16, row stride lda. Bt: (N,K) bf16. ACT: 0 none, 1 elu+1 for col<eluCut, 2 relu.
template<int ACT>
__global__ __launch_bounds__(256, 2) void gemm_bt_kernel(
    const short* __restrict__ A, const short* __restrict__ Bt,
    const float* __restrict__ bias, short* __restrict__ Cb,
    int N, int K, int lda, int ldc, int eluCut)
{
    __shared__ short As[4][128][8];   // [k-group][row][8 k-elems]
    __shared__ short Bs[4][128][8];
    const int tid = threadIdx.x;
    const int lane = tid & 63;
    const int wid = tid >> 6;
    const int wr = wid >> 1, wc = wid & 1;
    const int bm = blockIdx.x * 128, bn = blockIdx.y * 128;
    const int l15 = lane & 15, l4 = lane >> 4;

    const short* aSrc0 = A + (long)(bm + lane) * lda + wid * 8;
    const short* aSrc1 = A + (long)(bm + 64 + lane) * lda + wid * 8;
    const short* bSrc0 = Bt + (long)(bn + lane) * K + wid * 8;
    const short* bSrc1 = Bt + (long)(bn + 64 + lane) * K + wid * 8;

    f32x4 acc[4][4] = {};

    for (int k0 = 0; k0 < K; k0 += 32) {
        GLDS16(aSrc0 + k0, &As[wid][0][0]);
        GLDS16(aSrc1 + k0, &As[wid][64][0]);
        GLDS16(bSrc0 + k0, &Bs[wid][0][0]);
        GLDS16(bSrc1 + k0, &Bs[wid][64][0]);
        __syncthreads();
        s16x8 avA[4], avB[4];
#pragma unroll
        for (int m = 0; m < 4; ++m)
            avA[m] = *(const s16x8*)&As[l4][wr * 64 + m * 16 + l15][0];
#pragma unroll
        for (int n = 0; n < 4; ++n)
            avB[n] = *(const s16x8*)&Bs[l4][wc * 64 + n * 16 + l15][0];
#pragma unroll
        for (int m = 0; m < 4; ++m)
#pragma unroll
            for (int n = 0; n < 4; ++n)
                acc[m][n] = __builtin_amdgcn_mfma_f32_16x16x32_bf16(avA[m], avB[n], acc[m][n], 0, 0, 0);
        __syncthreads();
    }

#pragma unroll
    for (int m = 0; m < 4; ++m) {
        int row0 = bm + wr * 64 + m * 16 + l4 * 4;
#pragma unroll
        for (int n = 0; n < 4; ++n) {
            int col = bn + wc * 64 + n * 16 + l15;
            float bv = bias[col];
#pragma unroll
            for (int j = 0; j < 4; ++j) {
                float v = acc[m][n][j] + bv;
                if (ACT == 1) { if (col < eluCut) v = (v > 0.f) ? v + 1.f : __expf(v); }
                else if (ACT == 2) v = fmaxf(v, 0.f);
                Cb[(long)(row0 + j) * ldc + col] = f2bf(v);
            }
        }
    }
}

// ---- fused GEMM + bias + act + residual + LayerNorm (BM=64, BN=256, 8 waves) ----
// Wave w owns cols [w*32, w*32+32). out row = LN(act(A@Bt^T+bias) + Fin[row]).
template<int ACT>
__global__ __launch_bounds__(512, 4) void gemmln_kernel(
    const short* __restrict__ A, const short* __restrict__ Bt,
    const float* __restrict__ bias,
    const float* __restrict__ gam, const float* __restrict__ bet,
    const float* __restrict__ Fin, float* __restrict__ Fout,
    short* __restrict__ xb, int K, int lda)
{
    __shared__ short As[4][64][8];
    __shared__ short Bs[4][256][8];
    __shared__ float partS[8][64];
    __shared__ float partQ[8][64];
    __shared__ float muA[64];
    __shared__ float rsA[64];
    const int tid = threadIdx.x;
    const int lane = tid & 63;
    const int w = tid >> 6;          // wave id, 0..7; owns cols [w*32, w*32+32)
    const int bm = blockIdx.x * 64;
    const int l15 = lane & 15, l4 = lane >> 4;

    const short* aSrc = A + (long)(bm + lane) * lda + w * 8;

    f32x4 acc[4][2] = {};

    for (int k0 = 0; k0 < K; k0 += 32) {
        // A: waves 0-3 stage k-group w for all 64 rows (wave-uniform LDS base)
        if (w < 4)
            GLDS16(aSrc + k0, &As[w][0][0]);
        // B: 16 slices (4 k-groups x 4 row-blocks of 64); wave w does slices w and w+8.
#pragma unroll
        for (int jj = 0; jj < 2; ++jj) {
            int j = w + jj * 8;
            int kg = j & 3, rb = j >> 2;
            GLDS16(Bt + (long)(rb * 64 + lane) * K + k0 + kg * 8, &Bs[kg][rb * 64][0]);
        }
        __syncthreads();
        s16x8 avA[4], avB[2];
#pragma unroll
        for (int m = 0; m < 4; ++m)
            avA[m] = *(const s16x8*)&As[l4][m * 16 + l15][0];
#pragma unroll
        for (int n = 0; n < 2; ++n)
            avB[n] = *(const s16x8*)&Bs[l4][w * 32 + n * 16 + l15][0];
#pragma unroll
        for (int m = 0; m < 4; ++m)
#pragma unroll
            for (int n = 0; n < 2; ++n)
                acc[m][n] = __builtin_amdgcn_mfma_f32_16x16x32_bf16(avA[m], avB[n], acc[m][n], 0, 0, 0);
        __syncthreads();
    }

    // epilogue: bias + act + residual
#pragma unroll
    for (int m = 0; m < 4; ++m) {
#pragma unroll
        for (int n = 0; n < 2; ++n) {
            int col = w * 32 + n * 16 + l15;
            float bv = bias[col];
#pragma unroll
            for (int j = 0; j < 4; ++j) {
                int r = m * 16 + l4 * 4 + j;
                float v = acc[m][n][j] + bv;
                if (ACT == 2) v = fmaxf(v, 0.f);
                v += Fin[(long)(bm + r) * DIM + col];
                acc[m][n][j] = v;
            }
        }
    }
    // per-wave partial row sums (32 cols per wave)
#pragma unroll
    for (int m = 0; m < 4; ++m)
#pragma unroll
        for (int j = 0; j < 4; ++j) {
            float s = acc[m][0][j] + acc[m][1][j];
            float q = acc[m][0][j] * acc[m][0][j] + acc[m][1][j] * acc[m][1][j];
#pragma unroll
            for (int off = 1; off < 16; off <<= 1) {
                s += __shfl_xor(s, off);
                q += __shfl_xor(q, off);
            }
            if (l15 == 0) {
                partS[w][m * 16 + l4 * 4 + j] = s;
                partQ[w][m * 16 + l4 * 4 + j] = q;
            }
        }
    __syncthreads();
    if (tid < 64) {
        float S = 0, Qq = 0;
#pragma unroll
        for (int ww = 0; ww < 8; ++ww) { S += partS[ww][tid]; Qq += partQ[ww][tid]; }
        float mu = S * (1.f / 256.f);
        float var = Qq * (1.f / 256.f) - mu * mu;
        muA[tid] = mu;
        rsA[tid] = rsqrtf(var + 1e-3f);
    }
    __syncthreads();
#pragma unroll
    for (int m = 0; m < 4; ++m)
#pragma unroll
        for (int j = 0; j < 4; ++j) {
            int r = m * 16 + l4 * 4 + j;
            float mu = muA[r], rs = rsA[r];
#pragma unroll
            for (int n = 0; n < 2; ++n) {
                int col = w * 32 + n * 16 + l15;
                float t = (acc[m][n][j] - mu) * rs * gam[col] + bet[col];
                long o = (long)(bm + r) * DIM + col;
                xb[o] = f2bf(t);
                Fout[o] = t;
            }
        }
}

// ---------------- KV partial reduce: 512-row chunks, interleaved (M,512) KV buffer ----
__global__ __launch_bounds__(256) void kvpart_kernel(
    const short* __restrict__ KV, float* __restrict__ part)
{
    __shared__ float kfs[32][32];
    __shared__ float vsh[32][32];
    int c = blockIdx.x, bh = blockIdx.y;
    int b = bh >> 3, h = bh & 7;
    int tid = threadIdx.x;
    int d = tid >> 3, m0 = (tid & 7) * 4;
    float acc0 = 0, acc1 = 0, acc2 = 0, acc3 = 0, ks = 0;
    long rowBase = ((long)b * SEQ + c * 512) * 512 + h * DH;
    int lrow = (tid & 127) >> 2, cg = tid & 3;
    for (int s0 = 0; s0 < 512; s0 += 32) {
        long rb = rowBase + (long)(s0 + lrow) * 512 + cg * 8 + ((tid < 128) ? 0 : 256);
        s16x8 v8 = *(const s16x8*)(KV + rb);
        float* dst = (tid < 128) ? &kfs[lrow][cg * 8] : &vsh[lrow][cg * 8];
#pragma unroll
        for (int e = 0; e < 8; ++e) dst[e] = bf2f(v8[e]);
        __syncthreads();
#pragma unroll
        for (int s = 0; s < 32; ++s) {
            float kd = kfs[s][d];
            acc0 += kd * vsh[s][m0];
            acc1 += kd * vsh[s][m0 + 1];
            acc2 += kd * vsh[s][m0 + 2];
            acc3 += kd * vsh[s][m0 + 3];
        }
        if (tid < 32) {
#pragma unroll
            for (int s = 0; s < 32; ++s) ks += kfs[s][tid];
        }
        __syncthreads();
    }
    float* pb = part + ((long)bh * NCHUNK + c) * 1056;
    pb[tid * 4 + 0] = acc0; pb[tid * 4 + 1] = acc1;
    pb[tid * 4 + 2] = acc2; pb[tid * 4 + 3] = acc3;
    if (tid < 32) pb[1024 + tid] = ks;
}

__global__ __launch_bounds__(256) void kvred_kernel(
    const float* __restrict__ part, float* __restrict__ kv, float* __restrict__ ksum)
{
    int bh = blockIdx.x, tid = threadIdx.x;
    const float* pb = part + (long)bh * NCHUNK * 1056;
    float s0 = 0, s1 = 0, s2 = 0, s3 = 0;
    for (int cc = 0; cc < NCHUNK; ++cc) {
        const float* p = pb + cc * 1056 + tid * 4;
        s0 += p[0]; s1 += p[1]; s2 += p[2]; s3 += p[3];
    }
    float* kb = kv + (long)bh * 1024 + tid * 4;
    kb[0] = s0; kb[1] = s1; kb[2] = s2; kb[3] = s3;
    if (tid < 32) {
        float ss = 0;
        for (int cc = 0; cc < NCHUNK; ++cc) ss += pb[cc * 1056 + 1024 + tid];
        ksum[bh * 32 + tid] = ss;
    }
}

// ---------------- attention output: out = (Qf @ KV) * Z per (b,h); ld=512 -----------
__global__ __launch_bounds__(256) void attn_kernel(
    const short* __restrict__ Qf, const float* __restrict__ kv,
    const float* __restrict__ ksum, short* __restrict__ outp)
{
    __shared__ short kvbT[32][32];   // kvbT[m][d] = KV[d][m] bf16
    __shared__ float ksumf[32];
    __shared__ float zrow[128];
    const int LD = 512;
    int bh = blockIdx.y, b = bh >> 3, h = bh & 7;
    int l0 = blockIdx.x * 128;
    int tid = threadIdx.x;
    for (int j = tid; j < 1024; j += 256) {
        int dd = j >> 5, mm = j & 31;
        kvbT[mm][dd] = f2bf(kv[(long)bh * 1024 + j]);
    }
    if (tid < 32) ksumf[tid] = ksum[bh * 32 + tid];
    __syncthreads();
    if (tid < 128) {
        const s16x4* qp = (const s16x4*)(Qf + ((long)(b * SEQ + l0 + tid) * LD + h * DH));
        float den = 1e-6f;
#pragma unroll
        for (int jj = 0; jj < 8; ++jj) {
            s16x4 q4 = qp[jj];
#pragma unroll
            for (int e = 0; e < 4; ++e) den += bf2f(q4[e]) * ksumf[jj * 4 + e];
        }
        zrow[tid] = 1.f / den;
    }
    __syncthreads();
    int lane = tid & 63, wid = tid >> 6;
    int l15 = lane & 15, l4 = lane >> 4;
    s16x8 bfr[2];
#pragma unroll
    for (int n = 0; n < 2; ++n)
        bfr[n] = *(const s16x8*)&kvbT[n * 16 + l15][l4 * 8];
    f32x4 acc[2][2] = {};
#pragma unroll
    for (int m = 0; m < 2; ++m) {
        int rr = wid * 32 + m * 16 + l15;
        s16x8 a = *(const s16x8*)(Qf + ((long)(b * SEQ + l0 + rr) * LD + h * DH + l4 * 8));
#pragma unroll
        for (int n = 0; n < 2; ++n)
            acc[m][n] = __builtin_amdgcn_mfma_f32_16x16x32_bf16(a, bfr[n], acc[m][n], 0, 0, 0);
    }
#pragma unroll
    for (int m = 0; m < 2; ++m)
#pragma unroll
        for (int n = 0; n < 2; ++n)
#pragma unroll
            for (int j = 0; j < 4; ++j) {
                int rr = wid * 32 + m * 16 + l4 * 4 + j;
                int cc = n * 16 + l15;
                float v = acc[m][n][j] * zrow[rr];
                outp[(long)(b * SEQ + l0 + rr) * LD + h * DH + cc] = f2bf(v);
            }
}

// =======================================================================================
extern "C" void kernel_launch(void* const* d_in, const int* in_sizes, int n_in,
                              void* d_out, int out_size, void* d_ws, size_t ws_size,
                              hipStream_t stream)
{
    const float* Qin = (const float*)d_in[0];
    const float* Kin = (const float*)d_in[1];
    const float* Wq1 = (const float*)d_in[2];
    const float* Wk1 = (const float*)d_in[3];
    const float* Wv1 = (const float*)d_in[4];
    const float* Wo1 = (const float*)d_in[5];
    const float* bq1 = (const float*)d_in[6];
    const float* bk1 = (const float*)d_in[7];
    const float* bv1 = (const float*)d_in[8];
    const float* bo1 = (const float*)d_in[9];
    const float* Wq2 = (const float*)d_in[10];
    const float* Wk2 = (const float*)d_in[11];
    const float* Wv2 = (const float*)d_in[12];
    const float* Wo2 = (const float*)d_in[13];
    const float* bq2 = (const float*)d_in[14];
    const float* bk2 = (const float*)d_in[15];
    const float* bv2 = (const float*)d_in[16];
    const float* bo2 = (const float*)d_in[17];
    const float* Wf1 = (const float*)d_in[18];
    const float* bf1 = (const float*)d_in[19];
    const float* Wf2 = (const float*)d_in[20];
    const float* bf2 = (const float*)d_in[21];
    const float* ln1g = (const float*)d_in[22];
    const float* ln1b = (const float*)d_in[23];
    const float* ln2g = (const float*)d_in[24];
    const float* ln2b = (const float*)d_in[25];
    const float* ln3g = (const float*)d_in[26];
    const float* ln3b = (const float*)d_in[27];
    (void)in_sizes; (void)n_in; (void)out_size;

    const size_t NEED = 117841920ULL;   // proven budget from round 2; actual use ~115.8 MB
    if (ws_size < NEED) return;

    char* ws = (char*)d_ws;
    size_t off = 0;
    auto alloc = [&](size_t bytes) -> void* {
        void* p = ws + off;
        off = (off + bytes + 255) & ~(size_t)255;
        return p;
    };
    const size_t ACT_E = (size_t)M_TOTAL * DIM;  // 8388608 elems

    short* wkv1t = (short*)alloc((size_t)NL * 512 * 256 * 2);   // [Wk;Wv] stack, layer stride 512*256
    short* wkv2t = (short*)alloc((size_t)NL * 512 * 256 * 2);
    short* wq1t  = (short*)alloc((size_t)NL * 65536 * 2);
    short* wo1t  = (short*)alloc((size_t)NL * 65536 * 2);
    short* wq2t  = (short*)alloc((size_t)NL * 65536 * 2);
    short* wo2t  = (short*)alloc((size_t)NL * 65536 * 2);
    short* wf1t  = (short*)alloc((size_t)NL * 262144 * 2);
    short* wf2t  = (short*)alloc((size_t)NL * 262144 * 2);
    float* bkv1  = (float*)alloc((size_t)NL * 512 * 4);
    float* bkv2  = (float*)alloc((size_t)NL * 512 * 4);
    short* kbf = (short*)alloc(ACT_E * 2);          // K input as bf16
    short* A0  = (short*)alloc(ACT_E * 2);          // current x (bf16)
    short* BIG = (short*)alloc((size_t)M_TOTAL * 512 * 2);  // KV/Q/attnout | FFN hidden
    float* Fx  = (float*)alloc(ACT_E * 4);          // fp32 residual trunk
    float* part = (float*)alloc((size_t)64 * NCHUNK * 1056 * 4);
    float* kvb  = (float*)alloc((size_t)64 * 1024 * 4);
    float* ksb  = (float*)alloc((size_t)64 * 32 * 4);

    peadd_kernel<<<2048, 256, 0, stream>>>(Qin, A0, Fx, (int)ACT_E);
    kconv_kernel<<<2048, 256, 0, stream>>>(Kin, kbf, (int)ACT_E);
    wtrans_kernel<<<dim3(8, 8, NL), dim3(32, 8), 0, stream>>>(Wk1, wkv1t, 256, 256, 512 * 256, 0);
    wtrans_kernel<<<dim3(8, 8, NL), dim3(32, 8), 0, stream>>>(Wv1, wkv1t, 256, 256, 512 * 256, 256);
    wtrans_kernel<<<dim3(8, 8, NL), dim3(32, 8), 0, stream>>>(Wk2, wkv2t, 256, 256, 512 * 256, 0);
    wtrans_kernel<<<dim3(8, 8, NL), dim3(32, 8), 0, stream>>>(Wv2, wkv2t, 256, 256, 512 * 256, 256);
    wtrans_kernel<<<dim3(8, 8, NL), dim3(32, 8), 0, stream>>>(Wq1, wq1t, 256, 256, 65536, 0);
    wtrans_kernel<<<dim3(8, 8, NL), dim3(32, 8), 0, stream>>>(Wo1, wo1t, 256, 256, 65536, 0);
    wtrans_kernel<<<dim3(8, 8, NL), dim3(32, 8), 0, stream>>>(Wq2, wq2t, 256, 256, 65536, 0);
    wtrans_kernel<<<dim3(8, 8, NL), dim3(32, 8), 0, stream>>>(Wo2, wo2t, 256, 256, 65536, 0);
    wtrans_kernel<<<dim3(8, 32, NL), dim3(32, 8), 0, stream>>>(Wf1, wf1t, 256, 1024, 262144, 0);
    wtrans_kernel<<<dim3(32, 8, NL), dim3(32, 8), 0, stream>>>(Wf2, wf2t, 1024, 256, 262144, 0);
    bpack_kernel<<<NL, 512, 0, stream>>>(bk1, bv1, bk2, bv2, bkv1, bkv2);

    dim3 blk(256), blk512(512);

    for (int i = 0; i < NL; ++i) {
        const short* wkv1i = wkv1t + (size_t)i * 512 * 256;
        const short* wkv2i = wkv2t + (size_t)i * 512 * 256;
        const short* wq1i = wq1t + (size_t)i * 65536;
        const short* wo1i = wo1t + (size_t)i * 65536;
        const short* wq2i = wq2t + (size_t)i * 65536;
        const short* wo2i = wo2t + (size_t)i * 65536;
        const short* wf1i = wf1t + (size_t)i * 262144;
        const short* wf2i = wf2t + (size_t)i * 262144;

        // ---- self linear-attention (x1 -> x2)
        gemm_bt_kernel<1><<<dim3(256, 4), blk, 0, stream>>>(A0, wkv1i, bkv1 + i * 512, BIG, 512, 256, 256, 512, 256);
        kvpart_kernel<<<dim3(NCHUNK, 64), blk, 0, stream>>>(BIG, part);
        kvred_kernel<<<64, blk, 0, stream>>>(part, kvb, ksb);
        gemm_bt_kernel<1><<<dim3(256, 2), blk, 0, stream>>>(A0, wq1i, bq1 + i * 256, BIG, 256, 256, 256, 512, 256);
        attn_kernel<<<dim3(SEQ / 128, 64), blk, 0, stream>>>(BIG, kvb, ksb, BIG + 256);
        gemmln_kernel<0><<<M_TOTAL / 64, blk512, 0, stream>>>(BIG + 256, wo1i, bo1 + i * 256,
            ln1g + i * 256, ln1b + i * 256, Fx, Fx, A0, 256, 512);

        // ---- cross linear-attention (x2, K -> x3)
        gemm_bt_kernel<1><<<dim3(256, 4), blk, 0, stream>>>(kbf, wkv2i, bkv2 + i * 512, BIG, 512, 256, 256, 512, 256);
        kvpart_kernel<<<dim3(NCHUNK, 64), blk, 0, stream>>>(BIG, part);
        kvred_kernel<<<64, blk, 0, stream>>>(part, kvb, ksb);
        gemm_bt_kernel<1><<<dim3(256, 2), blk, 0, stream>>>(A0, wq2i, bq2 + i * 256, BIG, 256, 256, 256, 512, 256);
        attn_kernel<<<dim3(SEQ / 128, 64), blk, 0, stream>>>(BIG, kvb, ksb, BIG + 256);
        gemmln_kernel<0><<<M_TOTAL / 64, blk512, 0, stream>>>(BIG + 256, wo2i, bo2 + i * 256,
            ln2g + i * 256, ln2b + i * 256, Fx, Fx, A0, 256, 512);

        // ---- FFN (x3 -> x1'), 2 chunks of 16384 rows; hidden reuses BIG
        for (int c = 0; c < 2; ++c) {
            const size_t ro = (size_t)c * FFN_ROWS * DIM;
            gemm_bt_kernel<2><<<dim3(FFN_ROWS / 128, 8), blk, 0, stream>>>(
                A0 + ro, wf1i, bf1 + i * 1024, BIG, 1024, 256, 256, 1024, 0);
            float* foutC = ((i == NL - 1) ? (float*)d_out : Fx) + ro;
            gemmln_kernel<2><<<FFN_ROWS / 64, blk512, 0, stream>>>(BIG, wf2i, bf2 + i * 256,
                ln3g + i * 256, ln3b + i * 256, Fx + ro, foutC, A0 + ro, 1024, 1024);
        }
    }
}